// Round 1
// baseline (444.626 us; speedup 1.0000x reference)
//
#include <hip/hip_runtime.h>
#include <math.h>

#define NN 20000
#define NE 320000

// ---------------- CSR build ----------------
__global__ void count_kernel(const int* __restrict__ dst, int* __restrict__ counts) {
    int e = blockIdx.x * blockDim.x + threadIdx.x;
    if (e < NE) atomicAdd(&counts[dst[e]], 1);
}

__global__ __launch_bounds__(1024) void scan_kernel(const int* __restrict__ counts,
                                                    int* __restrict__ offsets,
                                                    int* __restrict__ cursor) {
    __shared__ int part[1024];
    const int T = 1024, CH = (NN + T - 1) / T;  // 20
    int t = threadIdx.x;
    int begin = t * CH;
    int end = begin + CH < NN ? begin + CH : NN;
    int s = 0;
    for (int i = begin; i < end; ++i) s += counts[i];
    part[t] = s;
    __syncthreads();
    for (int off = 1; off < T; off <<= 1) {
        int v = (t >= off) ? part[t - off] : 0;
        __syncthreads();
        part[t] += v;
        __syncthreads();
    }
    int run = (t == 0) ? 0 : part[t - 1];
    for (int i = begin; i < end; ++i) {
        offsets[i] = run;
        cursor[i] = run;
        run += counts[i];
    }
    if (t == T - 1) offsets[NN] = part[T - 1];
}

struct EdgeParams {
    const float *pw0, *pb0, *mu0, *is0;
    const float *pw1, *pb1, *mu1, *is1;
    const float *pw2, *pb2, *mu2, *is2;
};

__device__ inline void layer_w(float p0, float p1, const float* pw, const float* pb,
                               const float* mu, const float* is, float* out4) {
    // u_j = tanh(p0*pw[0][j] + p1*pw[1][j] + pb[j])
    float u0 = tanhf(p0 * pw[0] + p1 * pw[2] + pb[0]);
    float u1 = tanhf(p0 * pw[1] + p1 * pw[3] + pb[1]);
#pragma unroll
    for (int k = 0; k < 4; ++k) {
        float d0 = (u0 - mu[k * 2 + 0]) * is[k * 2 + 0];
        float d1 = (u1 - mu[k * 2 + 1]) * is[k * 2 + 1];
        out4[k] = expf(-0.5f * (d0 * d0 + d1 * d1));
    }
}

__global__ void fill_kernel(const int* __restrict__ src, const int* __restrict__ dst,
                            const float* __restrict__ pseudo, EdgeParams P,
                            int* __restrict__ cursor, int* __restrict__ csr_src,
                            float* __restrict__ csr_w /* [3][NE][4] */) {
    int e = blockIdx.x * blockDim.x + threadIdx.x;
    if (e >= NE) return;
    float p0 = pseudo[e * 2 + 0], p1 = pseudo[e * 2 + 1];
    int pos = atomicAdd(&cursor[dst[e]], 1);
    csr_src[pos] = src[e];
    float w[4];
    layer_w(p0, p1, P.pw0, P.pb0, P.mu0, P.is0, w);
    *(float4*)(csr_w + (size_t)(0 * NE + pos) * 4) = make_float4(w[0], w[1], w[2], w[3]);
    layer_w(p0, p1, P.pw1, P.pb1, P.mu1, P.is1, w);
    *(float4*)(csr_w + (size_t)(1 * NE + pos) * 4) = make_float4(w[0], w[1], w[2], w[3]);
    layer_w(p0, p1, P.pw2, P.pb2, P.mu2, P.is2, w);
    *(float4*)(csr_w + (size_t)(2 * NE + pos) * 4) = make_float4(w[0], w[1], w[2], w[3]);
}

// ---------------- weight re-layout: W2[(k*din+d)][o] = fc_w[d][k*128+o] ----------------
__global__ void prep_w2(const float* __restrict__ fc_w, float* __restrict__ w2, int din) {
    int idx = blockIdx.x * blockDim.x + threadIdx.x;
    int total = 4 * din * 128;
    if (idx >= total) return;
    int o = idx & 127;
    int kd = idx >> 7;
    int k = kd / din;
    int d = kd - k * din;
    w2[idx] = fc_w[d * 512 + k * 128 + o];
}

// ---------------- per-node weighted aggregation: t[n][k*DIN+d] ----------------
template <int DIN>
__global__ __launch_bounds__(64) void agg_kernel(const float* __restrict__ h,
                                                 const int* __restrict__ offsets,
                                                 const int* __restrict__ csr_src,
                                                 const float* __restrict__ csr_w,
                                                 float* __restrict__ t) {
    constexpr int J = DIN / 64;
    int n = blockIdx.x;
    int lane = threadIdx.x;
    int b = offsets[n], eN = offsets[n + 1];
    float acc[4][J];
#pragma unroll
    for (int k = 0; k < 4; ++k)
#pragma unroll
        for (int j = 0; j < J; ++j) acc[k][j] = 0.f;
    for (int i = b; i < eN; ++i) {
        int s = csr_src[i];
        float4 w = *(const float4*)(csr_w + (size_t)i * 4);
        float hv[J];
#pragma unroll
        for (int j = 0; j < J; ++j) hv[j] = h[(size_t)s * DIN + j * 64 + lane];
#pragma unroll
        for (int j = 0; j < J; ++j) {
            acc[0][j] += w.x * hv[j];
            acc[1][j] += w.y * hv[j];
            acc[2][j] += w.z * hv[j];
            acc[3][j] += w.w * hv[j];
        }
    }
#pragma unroll
    for (int k = 0; k < 4; ++k)
#pragma unroll
        for (int j = 0; j < J; ++j)
            t[(size_t)n * (4 * DIN) + k * DIN + j * 64 + lane] = acc[k][j];
}

// ---------------- fp32 tiled GEMM: C[M][128] = A[M][KD] @ B[KD][128] + bias ----------------
template <int KD>
__global__ __launch_bounds__(256) void gemm_kernel(const float* __restrict__ A,
                                                   const float* __restrict__ B,
                                                   const float* __restrict__ bias,
                                                   float* __restrict__ C, int M) {
    const int BM = 64, BN = 64, BK = 16;
    __shared__ float As[BK][BM + 1];
    __shared__ float Bs[BK][BN];
    int tid = threadIdx.x;
    int tx = tid & 15, ty = tid >> 4;
    int m0 = blockIdx.x * BM, n0 = blockIdx.y * BN;
    float c[4][4];
#pragma unroll
    for (int i = 0; i < 4; ++i)
#pragma unroll
        for (int j = 0; j < 4; ++j) c[i][j] = 0.f;

    int kA = tid & 15, mA0 = tid >> 4;
    int nB = tid & 63, kB0 = tid >> 6;

    for (int k0 = 0; k0 < KD; k0 += BK) {
#pragma unroll
        for (int r = 0; r < 4; ++r) {
            int m = mA0 + r * 16;
            int gm = m0 + m;
            As[kA][m] = (gm < M) ? A[(size_t)gm * KD + k0 + kA] : 0.f;
        }
#pragma unroll
        for (int r = 0; r < 4; ++r) {
            int k = kB0 + r * 4;
            Bs[k][nB] = B[(size_t)(k0 + k) * 128 + n0 + nB];
        }
        __syncthreads();
#pragma unroll
        for (int kk = 0; kk < BK; ++kk) {
            float a[4], bb[4];
#pragma unroll
            for (int i = 0; i < 4; ++i) a[i] = As[kk][ty * 4 + i];
#pragma unroll
            for (int j = 0; j < 4; ++j) bb[j] = Bs[kk][tx * 4 + j];
#pragma unroll
            for (int i = 0; i < 4; ++i)
#pragma unroll
                for (int j = 0; j < 4; ++j) c[i][j] += a[i] * bb[j];
        }
        __syncthreads();
    }
#pragma unroll
    for (int i = 0; i < 4; ++i) {
        int gm = m0 + ty * 4 + i;
        if (gm >= M) continue;
#pragma unroll
        for (int j = 0; j < 4; ++j) {
            int gn = n0 + tx * 4 + j;
            C[(size_t)gm * 128 + gn] = c[i][j] + bias[gn];
        }
    }
}

extern "C" void kernel_launch(void* const* d_in, const int* in_sizes, int n_in,
                              void* d_out, int out_size, void* d_ws, size_t ws_size,
                              hipStream_t stream) {
    const float* features = (const float*)d_in[0];
    const float* pseudo = (const float*)d_in[1];
    const int* src = (const int*)d_in[2];
    const int* dst = (const int*)d_in[3];
    const float* fc_w[3] = {(const float*)d_in[4], (const float*)d_in[10], (const float*)d_in[16]};
    const float* mu[3] = {(const float*)d_in[5], (const float*)d_in[11], (const float*)d_in[17]};
    const float* isg[3] = {(const float*)d_in[6], (const float*)d_in[12], (const float*)d_in[18]};
    const float* bias[3] = {(const float*)d_in[7], (const float*)d_in[13], (const float*)d_in[19]};
    const float* pw[3] = {(const float*)d_in[8], (const float*)d_in[14], (const float*)d_in[20]};
    const float* pb[3] = {(const float*)d_in[9], (const float*)d_in[15], (const float*)d_in[21]};

    char* ws = (char*)d_ws;
    auto alloc = [&](size_t bytes) -> void* {
        void* p = (void*)ws;
        ws += (bytes + 255) & ~(size_t)255;
        return p;
    };
    int* counts = (int*)alloc((size_t)NN * 4);
    int* offsets = (int*)alloc((size_t)(NN + 1) * 4);
    int* cursor = (int*)alloc((size_t)NN * 4);
    int* csr_src = (int*)alloc((size_t)NE * 4);
    float* csr_w = (float*)alloc((size_t)3 * NE * 4 * 4);
    float* w2_0 = (float*)alloc((size_t)256 * 128 * 4);
    float* w2_1 = (float*)alloc((size_t)512 * 128 * 4);
    float* w2_2 = (float*)alloc((size_t)512 * 128 * 4);
    float* tbuf = (float*)alloc((size_t)NN * 512 * 4);
    float* h1 = (float*)alloc((size_t)NN * 128 * 4);
    float* h2 = (float*)alloc((size_t)NN * 128 * 4);

    hipMemsetAsync(counts, 0, (size_t)NN * 4, stream);
    count_kernel<<<(NE + 255) / 256, 256, 0, stream>>>(dst, counts);
    scan_kernel<<<1, 1024, 0, stream>>>(counts, offsets, cursor);

    EdgeParams P;
    P.pw0 = pw[0]; P.pb0 = pb[0]; P.mu0 = mu[0]; P.is0 = isg[0];
    P.pw1 = pw[1]; P.pb1 = pb[1]; P.mu1 = mu[1]; P.is1 = isg[1];
    P.pw2 = pw[2]; P.pb2 = pb[2]; P.mu2 = mu[2]; P.is2 = isg[2];
    fill_kernel<<<(NE + 255) / 256, 256, 0, stream>>>(src, dst, pseudo, P, cursor, csr_src, csr_w);

    prep_w2<<<(4 * 64 * 128 + 255) / 256, 256, 0, stream>>>(fc_w[0], w2_0, 64);
    prep_w2<<<(4 * 128 * 128 + 255) / 256, 256, 0, stream>>>(fc_w[1], w2_1, 128);
    prep_w2<<<(4 * 128 * 128 + 255) / 256, 256, 0, stream>>>(fc_w[2], w2_2, 128);

    dim3 ggrid((NN + 63) / 64, 2);

    // layer 0: din=64
    agg_kernel<64><<<NN, 64, 0, stream>>>(features, offsets, csr_src, csr_w + (size_t)0 * NE * 4, tbuf);
    gemm_kernel<256><<<ggrid, 256, 0, stream>>>(tbuf, w2_0, bias[0], h1, NN);
    // layer 1: din=128
    agg_kernel<128><<<NN, 64, 0, stream>>>(h1, offsets, csr_src, csr_w + (size_t)1 * NE * 4, tbuf);
    gemm_kernel<512><<<ggrid, 256, 0, stream>>>(tbuf, w2_1, bias[1], h2, NN);
    // layer 2: din=128
    agg_kernel<128><<<NN, 64, 0, stream>>>(h2, offsets, csr_src, csr_w + (size_t)2 * NE * 4, tbuf);
    gemm_kernel<512><<<ggrid, 256, 0, stream>>>(tbuf, w2_2, bias[2], (float*)d_out, NN);
}

// Round 2
// 309.527 us; speedup vs baseline: 1.4365x; 1.4365x over previous
//
#include <hip/hip_runtime.h>
#include <hip/hip_bf16.h>
#include <math.h>

#define NN 20000
#define NE 320000

typedef __attribute__((ext_vector_type(8))) short bf16x8;
typedef __attribute__((ext_vector_type(4))) float f32x4;

// ---------------- CSR build ----------------
__global__ void count_kernel(const int* __restrict__ dst, int* __restrict__ counts) {
    int e = blockIdx.x * blockDim.x + threadIdx.x;
    if (e < NE) atomicAdd(&counts[dst[e]], 1);
}

__global__ __launch_bounds__(1024) void scan_kernel(const int* __restrict__ counts,
                                                    int* __restrict__ offsets,
                                                    int* __restrict__ cursor) {
    __shared__ int part[1024];
    const int T = 1024, CH = (NN + T - 1) / T;  // 20
    int t = threadIdx.x;
    int begin = t * CH;
    int end = begin + CH < NN ? begin + CH : NN;
    int s = 0;
    for (int i = begin; i < end; ++i) s += counts[i];
    part[t] = s;
    __syncthreads();
    for (int off = 1; off < T; off <<= 1) {
        int v = (t >= off) ? part[t - off] : 0;
        __syncthreads();
        part[t] += v;
        __syncthreads();
    }
    int run = (t == 0) ? 0 : part[t - 1];
    for (int i = begin; i < end; ++i) {
        offsets[i] = run;
        cursor[i] = run;
        run += counts[i];
    }
    if (t == T - 1) offsets[NN] = part[T - 1];
}

struct EdgeParams {
    const float *pw0, *pb0, *mu0, *is0;
    const float *pw1, *pb1, *mu1, *is1;
    const float *pw2, *pb2, *mu2, *is2;
};

__device__ inline void layer_w(float p0, float p1, const float* pw, const float* pb,
                               const float* mu, const float* is, float* out4) {
    float u0 = tanhf(p0 * pw[0] + p1 * pw[2] + pb[0]);
    float u1 = tanhf(p0 * pw[1] + p1 * pw[3] + pb[1]);
#pragma unroll
    for (int k = 0; k < 4; ++k) {
        float d0 = (u0 - mu[k * 2 + 0]) * is[k * 2 + 0];
        float d1 = (u1 - mu[k * 2 + 1]) * is[k * 2 + 1];
        out4[k] = expf(-0.5f * (d0 * d0 + d1 * d1));
    }
}

__global__ void fill_kernel(const int* __restrict__ src, const int* __restrict__ dst,
                            const float* __restrict__ pseudo, EdgeParams P,
                            int* __restrict__ cursor, int* __restrict__ csr_src,
                            float* __restrict__ csr_w /* [3][NE][4] */) {
    int e = blockIdx.x * blockDim.x + threadIdx.x;
    if (e >= NE) return;
    float p0 = pseudo[e * 2 + 0], p1 = pseudo[e * 2 + 1];
    int pos = atomicAdd(&cursor[dst[e]], 1);
    csr_src[pos] = src[e];
    float w[4];
    layer_w(p0, p1, P.pw0, P.pb0, P.mu0, P.is0, w);
    *(float4*)(csr_w + (size_t)(0 * NE + pos) * 4) = make_float4(w[0], w[1], w[2], w[3]);
    layer_w(p0, p1, P.pw1, P.pb1, P.mu1, P.is1, w);
    *(float4*)(csr_w + (size_t)(1 * NE + pos) * 4) = make_float4(w[0], w[1], w[2], w[3]);
    layer_w(p0, p1, P.pw2, P.pb2, P.mu2, P.is2, w);
    *(float4*)(csr_w + (size_t)(2 * NE + pos) * 4) = make_float4(w[0], w[1], w[2], w[3]);
}

// ---------------- weight re-layout (transposed, bf16): Bt[n][k*din+d] = fc_w[d][k*128+n] ----------------
__global__ void prep_w2t(const float* __restrict__ fc_w, __hip_bfloat16* __restrict__ w2t,
                         int din, int KD) {
    int idx = blockIdx.x * blockDim.x + threadIdx.x;
    if (idx >= 128 * KD) return;
    int n = idx / KD;
    int r = idx - n * KD;
    int k = r / din;
    int d = r - k * din;
    w2t[idx] = __float2bfloat16(fc_w[d * 512 + k * 128 + n]);
}

// ---------------- per-node weighted aggregation -> bf16 t[n][k*DIN+d] ----------------
template <int DIN>
__global__ __launch_bounds__(64) void agg_kernel(const float* __restrict__ h,
                                                 const int* __restrict__ offsets,
                                                 const int* __restrict__ csr_src,
                                                 const float* __restrict__ csr_w,
                                                 __hip_bfloat16* __restrict__ t) {
    constexpr int J = DIN / 64;
    int n = blockIdx.x;
    int lane = threadIdx.x;
    int b = offsets[n], eN = offsets[n + 1];
    float acc[4][J];
#pragma unroll
    for (int k = 0; k < 4; ++k)
#pragma unroll
        for (int j = 0; j < J; ++j) acc[k][j] = 0.f;

    int i = b;
    for (; i + 2 <= eN; i += 2) {
        int s0 = csr_src[i];
        int s1 = csr_src[i + 1];
        float4 w0 = *(const float4*)(csr_w + (size_t)i * 4);
        float4 w1 = *(const float4*)(csr_w + (size_t)(i + 1) * 4);
        float hv0[J], hv1[J];
#pragma unroll
        for (int j = 0; j < J; ++j) hv0[j] = h[(size_t)s0 * DIN + j * 64 + lane];
#pragma unroll
        for (int j = 0; j < J; ++j) hv1[j] = h[(size_t)s1 * DIN + j * 64 + lane];
#pragma unroll
        for (int j = 0; j < J; ++j) {
            acc[0][j] += w0.x * hv0[j] + w1.x * hv1[j];
            acc[1][j] += w0.y * hv0[j] + w1.y * hv1[j];
            acc[2][j] += w0.z * hv0[j] + w1.z * hv1[j];
            acc[3][j] += w0.w * hv0[j] + w1.w * hv1[j];
        }
    }
    if (i < eN) {
        int s0 = csr_src[i];
        float4 w0 = *(const float4*)(csr_w + (size_t)i * 4);
        float hv0[J];
#pragma unroll
        for (int j = 0; j < J; ++j) hv0[j] = h[(size_t)s0 * DIN + j * 64 + lane];
#pragma unroll
        for (int j = 0; j < J; ++j) {
            acc[0][j] += w0.x * hv0[j];
            acc[1][j] += w0.y * hv0[j];
            acc[2][j] += w0.z * hv0[j];
            acc[3][j] += w0.w * hv0[j];
        }
    }
#pragma unroll
    for (int k = 0; k < 4; ++k)
#pragma unroll
        for (int j = 0; j < J; ++j)
            t[(size_t)n * (4 * DIN) + k * DIN + j * 64 + lane] = __float2bfloat16(acc[k][j]);
}

// ---------------- bf16 MFMA GEMM: C[M][128] = A[M][KD] @ Bt[128][KD]^T + bias ----------------
// block = 128 threads (2 waves); tile 64 rows x 128 cols; wave w covers cols 64w..64w+63.
template <int KD>
__global__ __launch_bounds__(128) void mfma_gemm(const ushort* __restrict__ A,
                                                 const ushort* __restrict__ Bt,
                                                 const float* __restrict__ bias,
                                                 float* __restrict__ C, int M) {
    constexpr int PITCH = 40;  // 32 + 8 ushorts: 80 B rows, 16B-aligned, 2-way banks only
    __shared__ __align__(16) ushort As[64 * PITCH];
    __shared__ __align__(16) ushort Bs[128 * PITCH];
    int tid = threadIdx.x;
    int wave = tid >> 6, lane = tid & 63;
    int quad = lane >> 4, l16 = lane & 15;
    int m0 = blockIdx.x * 64;

    f32x4 acc[4][4];
#pragma unroll
    for (int r = 0; r < 4; ++r)
#pragma unroll
        for (int c = 0; c < 4; ++c) acc[r][c] = (f32x4){0.f, 0.f, 0.f, 0.f};

    for (int k0 = 0; k0 < KD; k0 += 32) {
        // stage A tile: 64 rows x 32 bf16 (4x16B chunks per row)
#pragma unroll
        for (int it = 0; it < 2; ++it) {
            int chunk = it * 128 + tid;
            int row = chunk >> 2, off = chunk & 3;
            int gm = m0 + row;
            uint4 v = make_uint4(0u, 0u, 0u, 0u);
            if (gm < M) v = *(const uint4*)(A + (size_t)gm * KD + k0 + off * 8);
            *(uint4*)(As + row * PITCH + off * 8) = v;
        }
        // stage B^T tile: 128 n-rows x 32 k
#pragma unroll
        for (int it = 0; it < 4; ++it) {
            int chunk = it * 128 + tid;
            int nr = chunk >> 2, off = chunk & 3;
            uint4 v = *(const uint4*)(Bt + (size_t)nr * KD + k0 + off * 8);
            *(uint4*)(Bs + nr * PITCH + off * 8) = v;
        }
        __syncthreads();

        bf16x8 afrag[4], bfrag[4];
#pragma unroll
        for (int r = 0; r < 4; ++r)
            afrag[r] = *(const bf16x8*)(As + (r * 16 + l16) * PITCH + quad * 8);
#pragma unroll
        for (int c = 0; c < 4; ++c)
            bfrag[c] = *(const bf16x8*)(Bs + (wave * 64 + c * 16 + l16) * PITCH + quad * 8);
#pragma unroll
        for (int r = 0; r < 4; ++r)
#pragma unroll
            for (int c = 0; c < 4; ++c)
                acc[r][c] = __builtin_amdgcn_mfma_f32_16x16x32_bf16(afrag[r], bfrag[c],
                                                                    acc[r][c], 0, 0, 0);
        __syncthreads();
    }

    // epilogue: D row = quad*4 + i, col = l16 within each 16x16 tile
#pragma unroll
    for (int c = 0; c < 4; ++c) {
        int gn = wave * 64 + c * 16 + l16;
        float bv = bias[gn];
#pragma unroll
        for (int r = 0; r < 4; ++r) {
            int gmb = m0 + r * 16 + quad * 4;
#pragma unroll
            for (int i = 0; i < 4; ++i) {
                int gm = gmb + i;
                if (gm < M) C[(size_t)gm * 128 + gn] = acc[r][c][i] + bv;
            }
        }
    }
}

extern "C" void kernel_launch(void* const* d_in, const int* in_sizes, int n_in,
                              void* d_out, int out_size, void* d_ws, size_t ws_size,
                              hipStream_t stream) {
    const float* features = (const float*)d_in[0];
    const float* pseudo = (const float*)d_in[1];
    const int* src = (const int*)d_in[2];
    const int* dst = (const int*)d_in[3];
    const float* fc_w[3] = {(const float*)d_in[4], (const float*)d_in[10], (const float*)d_in[16]};
    const float* mu[3] = {(const float*)d_in[5], (const float*)d_in[11], (const float*)d_in[17]};
    const float* isg[3] = {(const float*)d_in[6], (const float*)d_in[12], (const float*)d_in[18]};
    const float* bias[3] = {(const float*)d_in[7], (const float*)d_in[13], (const float*)d_in[19]};
    const float* pw[3] = {(const float*)d_in[8], (const float*)d_in[14], (const float*)d_in[20]};
    const float* pb[3] = {(const float*)d_in[9], (const float*)d_in[15], (const float*)d_in[21]};

    char* ws = (char*)d_ws;
    auto alloc = [&](size_t bytes) -> void* {
        void* p = (void*)ws;
        ws += (bytes + 255) & ~(size_t)255;
        return p;
    };
    int* counts = (int*)alloc((size_t)NN * 4);
    int* offsets = (int*)alloc((size_t)(NN + 1) * 4);
    int* cursor = (int*)alloc((size_t)NN * 4);
    int* csr_src = (int*)alloc((size_t)NE * 4);
    float* csr_w = (float*)alloc((size_t)3 * NE * 4 * 4);
    __hip_bfloat16* w2t_0 = (__hip_bfloat16*)alloc((size_t)128 * 256 * 2);
    __hip_bfloat16* w2t_1 = (__hip_bfloat16*)alloc((size_t)128 * 512 * 2);
    __hip_bfloat16* w2t_2 = (__hip_bfloat16*)alloc((size_t)128 * 512 * 2);
    __hip_bfloat16* tbuf = (__hip_bfloat16*)alloc((size_t)NN * 512 * 2);
    float* h1 = (float*)alloc((size_t)NN * 128 * 4);
    float* h2 = (float*)alloc((size_t)NN * 128 * 4);

    hipMemsetAsync(counts, 0, (size_t)NN * 4, stream);
    count_kernel<<<(NE + 255) / 256, 256, 0, stream>>>(dst, counts);
    scan_kernel<<<1, 1024, 0, stream>>>(counts, offsets, cursor);

    EdgeParams P;
    P.pw0 = pw[0]; P.pb0 = pb[0]; P.mu0 = mu[0]; P.is0 = isg[0];
    P.pw1 = pw[1]; P.pb1 = pb[1]; P.mu1 = mu[1]; P.is1 = isg[1];
    P.pw2 = pw[2]; P.pb2 = pb[2]; P.mu2 = mu[2]; P.is2 = isg[2];
    fill_kernel<<<(NE + 255) / 256, 256, 0, stream>>>(src, dst, pseudo, P, cursor, csr_src, csr_w);

    prep_w2t<<<(128 * 256 + 255) / 256, 256, 0, stream>>>(fc_w[0], w2t_0, 64, 256);
    prep_w2t<<<(128 * 512 + 255) / 256, 256, 0, stream>>>(fc_w[1], w2t_1, 128, 512);
    prep_w2t<<<(128 * 512 + 255) / 256, 256, 0, stream>>>(fc_w[2], w2t_2, 128, 512);

    const int GB = (NN + 63) / 64;  // 313

    // layer 0: din=64, KD=256
    agg_kernel<64><<<NN, 64, 0, stream>>>(features, offsets, csr_src,
                                          csr_w + (size_t)0 * NE * 4, tbuf);
    mfma_gemm<256><<<GB, 128, 0, stream>>>((const ushort*)tbuf, (const ushort*)w2t_0,
                                           bias[0], h1, NN);
    // layer 1: din=128, KD=512
    agg_kernel<128><<<NN, 64, 0, stream>>>(h1, offsets, csr_src,
                                           csr_w + (size_t)1 * NE * 4, tbuf);
    mfma_gemm<512><<<GB, 128, 0, stream>>>((const ushort*)tbuf, (const ushort*)w2t_1,
                                           bias[1], h2, NN);
    // layer 2: din=128, KD=512
    agg_kernel<128><<<NN, 64, 0, stream>>>(h2, offsets, csr_src,
                                           csr_w + (size_t)2 * NE * 4, tbuf);
    mfma_gemm<512><<<GB, 128, 0, stream>>>((const ushort*)tbuf, (const ushort*)w2t_2,
                                           bias[2], (float*)d_out, NN);
}

// Round 3
// 294.429 us; speedup vs baseline: 1.5101x; 1.0513x over previous
//
#include <hip/hip_runtime.h>
#include <hip/hip_bf16.h>
#include <math.h>

#define NN 20000
#define NE 320000

typedef __attribute__((ext_vector_type(8))) short bf16x8;
typedef __attribute__((ext_vector_type(4))) float f32x4;

__device__ inline float bf2f_lo(uint v) {
    union { uint i; float f; } c; c.i = v << 16; return c.f;
}
__device__ inline float bf2f_hi(uint v) {
    union { uint i; float f; } c; c.i = v & 0xffff0000u; return c.f;
}
__device__ inline ushort f2bf(float f) {
    __hip_bfloat16 h = __float2bfloat16(f);
    return *reinterpret_cast<ushort*>(&h);
}

// ---------------- CSR build ----------------
__global__ void count_kernel(const int* __restrict__ dst, int* __restrict__ counts) {
    int e = blockIdx.x * blockDim.x + threadIdx.x;
    if (e < NE) atomicAdd(&counts[dst[e]], 1);
}

__global__ __launch_bounds__(1024) void scan_kernel(const int* __restrict__ counts,
                                                    int* __restrict__ offsets,
                                                    int* __restrict__ cursor) {
    __shared__ int part[1024];
    const int T = 1024, CH = (NN + T - 1) / T;  // 20
    int t = threadIdx.x;
    int begin = t * CH;
    int end = begin + CH < NN ? begin + CH : NN;
    int s = 0;
    for (int i = begin; i < end; ++i) s += counts[i];
    part[t] = s;
    __syncthreads();
    for (int off = 1; off < T; off <<= 1) {
        int v = (t >= off) ? part[t - off] : 0;
        __syncthreads();
        part[t] += v;
        __syncthreads();
    }
    int run = (t == 0) ? 0 : part[t - 1];
    for (int i = begin; i < end; ++i) {
        offsets[i] = run;
        cursor[i] = run;
        run += counts[i];
    }
    if (t == T - 1) offsets[NN] = part[T - 1];
}

struct EdgeParams {
    const float *pw0, *pb0, *mu0, *is0;
    const float *pw1, *pb1, *mu1, *is1;
    const float *pw2, *pb2, *mu2, *is2;
};

__device__ inline float fast_tanh(float x) {
    x = fminf(fmaxf(x, -9.f), 9.f);
    float e = __expf(2.f * x);
    return 1.f - 2.f / (e + 1.f);
}

__device__ inline void layer_w(float p0, float p1, const float* pw, const float* pb,
                               const float* mu, const float* is, float* out4) {
    float u0 = fast_tanh(p0 * pw[0] + p1 * pw[2] + pb[0]);
    float u1 = fast_tanh(p0 * pw[1] + p1 * pw[3] + pb[1]);
#pragma unroll
    for (int k = 0; k < 4; ++k) {
        float d0 = (u0 - mu[k * 2 + 0]) * is[k * 2 + 0];
        float d1 = (u1 - mu[k * 2 + 1]) * is[k * 2 + 1];
        out4[k] = __expf(-0.5f * (d0 * d0 + d1 * d1));
    }
}

__global__ void fill_kernel(const int* __restrict__ src, const int* __restrict__ dst,
                            const float* __restrict__ pseudo, EdgeParams P,
                            int* __restrict__ cursor, int* __restrict__ csr_src,
                            float* __restrict__ csr_w /* [3][NE][4] */) {
    int e = blockIdx.x * blockDim.x + threadIdx.x;
    if (e >= NE) return;
    float p0 = pseudo[e * 2 + 0], p1 = pseudo[e * 2 + 1];
    int pos = atomicAdd(&cursor[dst[e]], 1);
    csr_src[pos] = src[e];
    float w[4];
    layer_w(p0, p1, P.pw0, P.pb0, P.mu0, P.is0, w);
    *(float4*)(csr_w + (size_t)(0 * NE + pos) * 4) = make_float4(w[0], w[1], w[2], w[3]);
    layer_w(p0, p1, P.pw1, P.pb1, P.mu1, P.is1, w);
    *(float4*)(csr_w + (size_t)(1 * NE + pos) * 4) = make_float4(w[0], w[1], w[2], w[3]);
    layer_w(p0, p1, P.pw2, P.pb2, P.mu2, P.is2, w);
    *(float4*)(csr_w + (size_t)(2 * NE + pos) * 4) = make_float4(w[0], w[1], w[2], w[3]);
}

// ---------------- merged weight re-layout (transposed, bf16) ----------------
// Bt[n][k*din+d] = fc_w[d][k*128+n]
__global__ void prep_all(const float* __restrict__ f0, const float* __restrict__ f1,
                         const float* __restrict__ f2, ushort* __restrict__ w0,
                         ushort* __restrict__ w1, ushort* __restrict__ w2) {
    int idx = blockIdx.x * blockDim.x + threadIdx.x;
    const float* srcp;
    ushort* dstp;
    int din, KD, li;
    if (idx < 128 * 256) {
        srcp = f0; dstp = w0; din = 64; KD = 256; li = idx;
    } else if (idx < 128 * 256 + 128 * 512) {
        srcp = f1; dstp = w1; din = 128; KD = 512; li = idx - 128 * 256;
    } else if (idx < 128 * 256 + 2 * 128 * 512) {
        srcp = f2; dstp = w2; din = 128; KD = 512; li = idx - 128 * 256 - 128 * 512;
    } else {
        return;
    }
    int n = li / KD;
    int r = li - n * KD;
    int k = r / din;
    int d = r - k * din;
    dstp[li] = f2bf(srcp[d * 512 + k * 128 + n]);
}

// ---------------- layer-0 aggregation (fp32 features) -> bf16 t[n][k*64+d] ----------------
__global__ __launch_bounds__(64) void agg_f32_64(const float* __restrict__ h,
                                                 const int* __restrict__ offsets,
                                                 const int* __restrict__ csr_src,
                                                 const float* __restrict__ csr_w,
                                                 ushort* __restrict__ t) {
    int n = blockIdx.x;
    int lane = threadIdx.x;
    int b = offsets[n], eN = offsets[n + 1];
    float acc[4] = {0.f, 0.f, 0.f, 0.f};
    int i = b;
    for (; i + 2 <= eN; i += 2) {
        int s0 = csr_src[i], s1 = csr_src[i + 1];
        float4 w0 = *(const float4*)(csr_w + (size_t)i * 4);
        float4 w1 = *(const float4*)(csr_w + (size_t)(i + 1) * 4);
        float hv0 = h[(size_t)s0 * 64 + lane];
        float hv1 = h[(size_t)s1 * 64 + lane];
        acc[0] += w0.x * hv0 + w1.x * hv1;
        acc[1] += w0.y * hv0 + w1.y * hv1;
        acc[2] += w0.z * hv0 + w1.z * hv1;
        acc[3] += w0.w * hv0 + w1.w * hv1;
    }
    if (i < eN) {
        int s0 = csr_src[i];
        float4 w0 = *(const float4*)(csr_w + (size_t)i * 4);
        float hv0 = h[(size_t)s0 * 64 + lane];
        acc[0] += w0.x * hv0;
        acc[1] += w0.y * hv0;
        acc[2] += w0.z * hv0;
        acc[3] += w0.w * hv0;
    }
#pragma unroll
    for (int k = 0; k < 4; ++k) t[(size_t)n * 256 + k * 64 + lane] = f2bf(acc[k]);
}

// ---------------- layer-1/2 aggregation (bf16 h, packed uint loads) -> bf16 t ----------------
__global__ __launch_bounds__(64) void agg_bf_128(const ushort* __restrict__ h,
                                                 const int* __restrict__ offsets,
                                                 const int* __restrict__ csr_src,
                                                 const float* __restrict__ csr_w,
                                                 ushort* __restrict__ t) {
    int n = blockIdx.x;
    int lane = threadIdx.x;
    int b = offsets[n], eN = offsets[n + 1];
    float acc[4][2];
#pragma unroll
    for (int k = 0; k < 4; ++k) { acc[k][0] = 0.f; acc[k][1] = 0.f; }
    int i = b;
    for (; i + 2 <= eN; i += 2) {
        int s0 = csr_src[i], s1 = csr_src[i + 1];
        float4 w0 = *(const float4*)(csr_w + (size_t)i * 4);
        float4 w1 = *(const float4*)(csr_w + (size_t)(i + 1) * 4);
        uint v0 = *(const uint*)(h + (size_t)s0 * 128 + lane * 2);
        uint v1 = *(const uint*)(h + (size_t)s1 * 128 + lane * 2);
        float a0 = bf2f_lo(v0), a1 = bf2f_hi(v0);
        float b0 = bf2f_lo(v1), b1 = bf2f_hi(v1);
        acc[0][0] += w0.x * a0 + w1.x * b0;
        acc[0][1] += w0.x * a1 + w1.x * b1;
        acc[1][0] += w0.y * a0 + w1.y * b0;
        acc[1][1] += w0.y * a1 + w1.y * b1;
        acc[2][0] += w0.z * a0 + w1.z * b0;
        acc[2][1] += w0.z * a1 + w1.z * b1;
        acc[3][0] += w0.w * a0 + w1.w * b0;
        acc[3][1] += w0.w * a1 + w1.w * b1;
    }
    if (i < eN) {
        int s0 = csr_src[i];
        float4 w0 = *(const float4*)(csr_w + (size_t)i * 4);
        uint v0 = *(const uint*)(h + (size_t)s0 * 128 + lane * 2);
        float a0 = bf2f_lo(v0), a1 = bf2f_hi(v0);
        acc[0][0] += w0.x * a0; acc[0][1] += w0.x * a1;
        acc[1][0] += w0.y * a0; acc[1][1] += w0.y * a1;
        acc[2][0] += w0.z * a0; acc[2][1] += w0.z * a1;
        acc[3][0] += w0.w * a0; acc[3][1] += w0.w * a1;
    }
#pragma unroll
    for (int k = 0; k < 4; ++k) {
        ushort2 p;
        p.x = f2bf(acc[k][0]);
        p.y = f2bf(acc[k][1]);
        *(ushort2*)(t + (size_t)n * 512 + k * 128 + lane * 2) = p;
    }
}

// ---------------- bf16 MFMA GEMM: C[M][128] = A[M][KD] @ Bt[128][KD]^T + bias ----------------
template <int KD, bool OUTBF>
__global__ __launch_bounds__(128) void mfma_gemm(const ushort* __restrict__ A,
                                                 const ushort* __restrict__ Bt,
                                                 const float* __restrict__ bias,
                                                 void* __restrict__ Cout, int M) {
    constexpr int PITCH = 40;  // 32 + 8 ushorts: 80 B rows, 16B-aligned, 2-way banks only
    __shared__ __align__(16) ushort As[64 * PITCH];
    __shared__ __align__(16) ushort Bs[128 * PITCH];
    int tid = threadIdx.x;
    int wave = tid >> 6, lane = tid & 63;
    int quad = lane >> 4, l16 = lane & 15;
    int m0 = blockIdx.x * 64;

    f32x4 acc[4][4];
#pragma unroll
    for (int r = 0; r < 4; ++r)
#pragma unroll
        for (int c = 0; c < 4; ++c) acc[r][c] = (f32x4){0.f, 0.f, 0.f, 0.f};

    for (int k0 = 0; k0 < KD; k0 += 32) {
#pragma unroll
        for (int it = 0; it < 2; ++it) {
            int chunk = it * 128 + tid;
            int row = chunk >> 2, off = chunk & 3;
            int gm = m0 + row;
            uint4 v = make_uint4(0u, 0u, 0u, 0u);
            if (gm < M) v = *(const uint4*)(A + (size_t)gm * KD + k0 + off * 8);
            *(uint4*)(As + row * PITCH + off * 8) = v;
        }
#pragma unroll
        for (int it = 0; it < 4; ++it) {
            int chunk = it * 128 + tid;
            int nr = chunk >> 2, off = chunk & 3;
            uint4 v = *(const uint4*)(Bt + (size_t)nr * KD + k0 + off * 8);
            *(uint4*)(Bs + nr * PITCH + off * 8) = v;
        }
        __syncthreads();

        bf16x8 afrag[4], bfrag[4];
#pragma unroll
        for (int r = 0; r < 4; ++r)
            afrag[r] = *(const bf16x8*)(As + (r * 16 + l16) * PITCH + quad * 8);
#pragma unroll
        for (int c = 0; c < 4; ++c)
            bfrag[c] = *(const bf16x8*)(Bs + (wave * 64 + c * 16 + l16) * PITCH + quad * 8);
#pragma unroll
        for (int r = 0; r < 4; ++r)
#pragma unroll
            for (int c = 0; c < 4; ++c)
                acc[r][c] = __builtin_amdgcn_mfma_f32_16x16x32_bf16(afrag[r], bfrag[c],
                                                                    acc[r][c], 0, 0, 0);
        __syncthreads();
    }

#pragma unroll
    for (int c = 0; c < 4; ++c) {
        int gn = wave * 64 + c * 16 + l16;
        float bv = bias[gn];
#pragma unroll
        for (int r = 0; r < 4; ++r) {
            int gmb = m0 + r * 16 + quad * 4;
#pragma unroll
            for (int i = 0; i < 4; ++i) {
                int gm = gmb + i;
                if (gm < M) {
                    float val = acc[r][c][i] + bv;
                    if (OUTBF)
                        ((ushort*)Cout)[(size_t)gm * 128 + gn] = f2bf(val);
                    else
                        ((float*)Cout)[(size_t)gm * 128 + gn] = val;
                }
            }
        }
    }
}

extern "C" void kernel_launch(void* const* d_in, const int* in_sizes, int n_in,
                              void* d_out, int out_size, void* d_ws, size_t ws_size,
                              hipStream_t stream) {
    const float* features = (const float*)d_in[0];
    const float* pseudo = (const float*)d_in[1];
    const int* src = (const int*)d_in[2];
    const int* dst = (const int*)d_in[3];
    const float* fc_w[3] = {(const float*)d_in[4], (const float*)d_in[10], (const float*)d_in[16]};
    const float* mu[3] = {(const float*)d_in[5], (const float*)d_in[11], (const float*)d_in[17]};
    const float* isg[3] = {(const float*)d_in[6], (const float*)d_in[12], (const float*)d_in[18]};
    const float* bias[3] = {(const float*)d_in[7], (const float*)d_in[13], (const float*)d_in[19]};
    const float* pw[3] = {(const float*)d_in[8], (const float*)d_in[14], (const float*)d_in[20]};
    const float* pb[3] = {(const float*)d_in[9], (const float*)d_in[15], (const float*)d_in[21]};

    char* ws = (char*)d_ws;
    auto alloc = [&](size_t bytes) -> void* {
        void* p = (void*)ws;
        ws += (bytes + 255) & ~(size_t)255;
        return p;
    };
    int* counts = (int*)alloc((size_t)NN * 4);
    int* offsets = (int*)alloc((size_t)(NN + 1) * 4);
    int* cursor = (int*)alloc((size_t)NN * 4);
    int* csr_src = (int*)alloc((size_t)NE * 4);
    float* csr_w = (float*)alloc((size_t)3 * NE * 4 * 4);
    ushort* w2t_0 = (ushort*)alloc((size_t)128 * 256 * 2);
    ushort* w2t_1 = (ushort*)alloc((size_t)128 * 512 * 2);
    ushort* w2t_2 = (ushort*)alloc((size_t)128 * 512 * 2);
    ushort* tbuf = (ushort*)alloc((size_t)NN * 512 * 2);
    ushort* h1 = (ushort*)alloc((size_t)NN * 128 * 2);
    ushort* h2 = (ushort*)alloc((size_t)NN * 128 * 2);

    hipMemsetAsync(counts, 0, (size_t)NN * 4, stream);
    count_kernel<<<(NE + 255) / 256, 256, 0, stream>>>(dst, counts);
    scan_kernel<<<1, 1024, 0, stream>>>(counts, offsets, cursor);

    EdgeParams P;
    P.pw0 = pw[0]; P.pb0 = pb[0]; P.mu0 = mu[0]; P.is0 = isg[0];
    P.pw1 = pw[1]; P.pb1 = pb[1]; P.mu1 = mu[1]; P.is1 = isg[1];
    P.pw2 = pw[2]; P.pb2 = pb[2]; P.mu2 = mu[2]; P.is2 = isg[2];
    fill_kernel<<<(NE + 255) / 256, 256, 0, stream>>>(src, dst, pseudo, P, cursor, csr_src, csr_w);

    const int PT = 128 * 256 + 2 * 128 * 512;
    prep_all<<<(PT + 255) / 256, 256, 0, stream>>>(fc_w[0], fc_w[1], fc_w[2], w2t_0, w2t_1, w2t_2);

    const int GB = (NN + 63) / 64;  // 313

    // layer 0: din=64, KD=256
    agg_f32_64<<<NN, 64, 0, stream>>>(features, offsets, csr_src, csr_w + (size_t)0 * NE * 4, tbuf);
    mfma_gemm<256, true><<<GB, 128, 0, stream>>>(tbuf, w2t_0, bias[0], h1, NN);
    // layer 1: din=128, KD=512
    agg_bf_128<<<NN, 64, 0, stream>>>(h1, offsets, csr_src, csr_w + (size_t)1 * NE * 4, tbuf);
    mfma_gemm<512, true><<<GB, 128, 0, stream>>>(tbuf, w2t_1, bias[1], h2, NN);
    // layer 2: din=128, KD=512
    agg_bf_128<<<NN, 64, 0, stream>>>(h2, offsets, csr_src, csr_w + (size_t)2 * NE * 4, tbuf);
    mfma_gemm<512, false><<<GB, 128, 0, stream>>>(tbuf, w2t_2, bias[2], (float*)d_out, NN);
}

// Round 4
// 287.849 us; speedup vs baseline: 1.5446x; 1.0229x over previous
//
#include <hip/hip_runtime.h>
#include <hip/hip_bf16.h>
#include <math.h>

#define NN 20000
#define NE 320000

typedef __attribute__((ext_vector_type(8))) short bf16x8;
typedef __attribute__((ext_vector_type(4))) float f32x4;

__device__ inline float bf2f_lo(uint v) {
    union { uint i; float f; } c; c.i = v << 16; return c.f;
}
__device__ inline float bf2f_hi(uint v) {
    union { uint i; float f; } c; c.i = v & 0xffff0000u; return c.f;
}
__device__ inline ushort f2bf(float f) {
    __hip_bfloat16 h = __float2bfloat16(f);
    return *reinterpret_cast<ushort*>(&h);
}

// ---------------- CSR build ----------------
__global__ void count_kernel(const int* __restrict__ dst, int* __restrict__ counts) {
    int e = blockIdx.x * blockDim.x + threadIdx.x;
    if (e < NE) atomicAdd(&counts[dst[e]], 1);
}

__global__ __launch_bounds__(1024) void scan_kernel(const int* __restrict__ counts,
                                                    int* __restrict__ offsets,
                                                    int* __restrict__ cursor) {
    __shared__ int part[1024];
    const int T = 1024, CH = (NN + T - 1) / T;  // 20
    int t = threadIdx.x;
    int begin = t * CH;
    int end = begin + CH < NN ? begin + CH : NN;
    int s = 0;
    for (int i = begin; i < end; ++i) s += counts[i];
    part[t] = s;
    __syncthreads();
    for (int off = 1; off < T; off <<= 1) {
        int v = (t >= off) ? part[t - off] : 0;
        __syncthreads();
        part[t] += v;
        __syncthreads();
    }
    int run = (t == 0) ? 0 : part[t - 1];
    for (int i = begin; i < end; ++i) {
        offsets[i] = run;
        cursor[i] = run;
        run += counts[i];
    }
    if (t == T - 1) offsets[NN] = part[T - 1];
}

// pass 1: scatter ONLY the 4-byte edge index into CSR position order
__global__ void fill1_kernel(const int* __restrict__ dst, int* __restrict__ cursor,
                             int* __restrict__ csr_eidx) {
    int e = blockIdx.x * blockDim.x + threadIdx.x;
    if (e >= NE) return;
    int pos = atomicAdd(&cursor[dst[e]], 1);
    csr_eidx[pos] = e;
}

struct EdgeParams {
    const float *pw0, *pb0, *mu0, *is0;
    const float *pw1, *pb1, *mu1, *is1;
    const float *pw2, *pb2, *mu2, *is2;
};

__device__ inline float fast_tanh(float x) {
    x = fminf(fmaxf(x, -9.f), 9.f);
    float e = __expf(2.f * x);
    return 1.f - 2.f / (e + 1.f);
}

__device__ inline void layer_w(float p0, float p1, const float* pw, const float* pb,
                               const float* mu, const float* is, float* out4) {
    float u0 = fast_tanh(p0 * pw[0] + p1 * pw[2] + pb[0]);
    float u1 = fast_tanh(p0 * pw[1] + p1 * pw[3] + pb[1]);
#pragma unroll
    for (int k = 0; k < 4; ++k) {
        float d0 = (u0 - mu[k * 2 + 0]) * is[k * 2 + 0];
        float d1 = (u1 - mu[k * 2 + 1]) * is[k * 2 + 1];
        out4[k] = __expf(-0.5f * (d0 * d0 + d1 * d1));
    }
}

// pass 2: pos-order; random READS of pseudo/src, dense coalesced WRITES of weights+src
__global__ void fill2_kernel(const int* __restrict__ csr_eidx, const int* __restrict__ src,
                             const float* __restrict__ pseudo, EdgeParams P,
                             int* __restrict__ csr_src,
                             float* __restrict__ csr_w /* [3][NE][4] */) {
    int i = blockIdx.x * blockDim.x + threadIdx.x;
    if (i >= NE) return;
    int e = csr_eidx[i];
    float2 p = *(const float2*)(pseudo + (size_t)e * 2);
    csr_src[i] = src[e];
    float w[4];
    layer_w(p.x, p.y, P.pw0, P.pb0, P.mu0, P.is0, w);
    *(float4*)(csr_w + (size_t)(0 * NE + i) * 4) = make_float4(w[0], w[1], w[2], w[3]);
    layer_w(p.x, p.y, P.pw1, P.pb1, P.mu1, P.is1, w);
    *(float4*)(csr_w + (size_t)(1 * NE + i) * 4) = make_float4(w[0], w[1], w[2], w[3]);
    layer_w(p.x, p.y, P.pw2, P.pb2, P.mu2, P.is2, w);
    *(float4*)(csr_w + (size_t)(2 * NE + i) * 4) = make_float4(w[0], w[1], w[2], w[3]);
}

// ---------------- merged weight re-layout (transposed, bf16) ----------------
// Bt[n][k*din+d] = fc_w[d][k*128+n]
__global__ void prep_all(const float* __restrict__ f0, const float* __restrict__ f1,
                         const float* __restrict__ f2, ushort* __restrict__ w0,
                         ushort* __restrict__ w1, ushort* __restrict__ w2) {
    int idx = blockIdx.x * blockDim.x + threadIdx.x;
    const float* srcp;
    ushort* dstp;
    int din, KD, li;
    if (idx < 128 * 256) {
        srcp = f0; dstp = w0; din = 64; KD = 256; li = idx;
    } else if (idx < 128 * 256 + 128 * 512) {
        srcp = f1; dstp = w1; din = 128; KD = 512; li = idx - 128 * 256;
    } else if (idx < 128 * 256 + 2 * 128 * 512) {
        srcp = f2; dstp = w2; din = 128; KD = 512; li = idx - 128 * 256 - 128 * 512;
    } else {
        return;
    }
    int n = li / KD;
    int r = li - n * KD;
    int k = r / din;
    int d = r - k * din;
    dstp[li] = f2bf(srcp[d * 512 + k * 128 + n]);
}

// ---------------- layer-0 aggregation (fp32 features) -> bf16 t[n][k*64+d] ----------------
__global__ __launch_bounds__(64) void agg_f32_64(const float* __restrict__ h,
                                                 const int* __restrict__ offsets,
                                                 const int* __restrict__ csr_src,
                                                 const float* __restrict__ csr_w,
                                                 ushort* __restrict__ t) {
    int n = blockIdx.x;
    int lane = threadIdx.x;
    int b = offsets[n], eN = offsets[n + 1];
    float acc[4] = {0.f, 0.f, 0.f, 0.f};
    int i = b;
    for (; i + 4 <= eN; i += 4) {
        int s0 = csr_src[i], s1 = csr_src[i + 1], s2 = csr_src[i + 2], s3 = csr_src[i + 3];
        float4 w0 = *(const float4*)(csr_w + (size_t)i * 4);
        float4 w1 = *(const float4*)(csr_w + (size_t)(i + 1) * 4);
        float4 w2 = *(const float4*)(csr_w + (size_t)(i + 2) * 4);
        float4 w3 = *(const float4*)(csr_w + (size_t)(i + 3) * 4);
        float hv0 = h[(size_t)s0 * 64 + lane];
        float hv1 = h[(size_t)s1 * 64 + lane];
        float hv2 = h[(size_t)s2 * 64 + lane];
        float hv3 = h[(size_t)s3 * 64 + lane];
        acc[0] += w0.x * hv0 + w1.x * hv1 + w2.x * hv2 + w3.x * hv3;
        acc[1] += w0.y * hv0 + w1.y * hv1 + w2.y * hv2 + w3.y * hv3;
        acc[2] += w0.z * hv0 + w1.z * hv1 + w2.z * hv2 + w3.z * hv3;
        acc[3] += w0.w * hv0 + w1.w * hv1 + w2.w * hv2 + w3.w * hv3;
    }
    for (; i < eN; ++i) {
        int s0 = csr_src[i];
        float4 w0 = *(const float4*)(csr_w + (size_t)i * 4);
        float hv0 = h[(size_t)s0 * 64 + lane];
        acc[0] += w0.x * hv0;
        acc[1] += w0.y * hv0;
        acc[2] += w0.z * hv0;
        acc[3] += w0.w * hv0;
    }
#pragma unroll
    for (int k = 0; k < 4; ++k) t[(size_t)n * 256 + k * 64 + lane] = f2bf(acc[k]);
}

// ---------------- layer-1/2 aggregation (bf16 h, packed uint loads) -> bf16 t ----------------
__global__ __launch_bounds__(64) void agg_bf_128(const ushort* __restrict__ h,
                                                 const int* __restrict__ offsets,
                                                 const int* __restrict__ csr_src,
                                                 const float* __restrict__ csr_w,
                                                 ushort* __restrict__ t) {
    int n = blockIdx.x;
    int lane = threadIdx.x;
    int b = offsets[n], eN = offsets[n + 1];
    float acc[4][2];
#pragma unroll
    for (int k = 0; k < 4; ++k) { acc[k][0] = 0.f; acc[k][1] = 0.f; }
    int i = b;
    for (; i + 4 <= eN; i += 4) {
        int s0 = csr_src[i], s1 = csr_src[i + 1], s2 = csr_src[i + 2], s3 = csr_src[i + 3];
        float4 w0 = *(const float4*)(csr_w + (size_t)i * 4);
        float4 w1 = *(const float4*)(csr_w + (size_t)(i + 1) * 4);
        float4 w2 = *(const float4*)(csr_w + (size_t)(i + 2) * 4);
        float4 w3 = *(const float4*)(csr_w + (size_t)(i + 3) * 4);
        uint v0 = *(const uint*)(h + (size_t)s0 * 128 + lane * 2);
        uint v1 = *(const uint*)(h + (size_t)s1 * 128 + lane * 2);
        uint v2 = *(const uint*)(h + (size_t)s2 * 128 + lane * 2);
        uint v3 = *(const uint*)(h + (size_t)s3 * 128 + lane * 2);
        float a0 = bf2f_lo(v0), a1 = bf2f_hi(v0);
        float b0 = bf2f_lo(v1), b1 = bf2f_hi(v1);
        float c0 = bf2f_lo(v2), c1 = bf2f_hi(v2);
        float d0 = bf2f_lo(v3), d1 = bf2f_hi(v3);
        acc[0][0] += w0.x * a0 + w1.x * b0 + w2.x * c0 + w3.x * d0;
        acc[0][1] += w0.x * a1 + w1.x * b1 + w2.x * c1 + w3.x * d1;
        acc[1][0] += w0.y * a0 + w1.y * b0 + w2.y * c0 + w3.y * d0;
        acc[1][1] += w0.y * a1 + w1.y * b1 + w2.y * c1 + w3.y * d1;
        acc[2][0] += w0.z * a0 + w1.z * b0 + w2.z * c0 + w3.z * d0;
        acc[2][1] += w0.z * a1 + w1.z * b1 + w2.z * c1 + w3.z * d1;
        acc[3][0] += w0.w * a0 + w1.w * b0 + w2.w * c0 + w3.w * d0;
        acc[3][1] += w0.w * a1 + w1.w * b1 + w2.w * c1 + w3.w * d1;
    }
    for (; i < eN; ++i) {
        int s0 = csr_src[i];
        float4 w0 = *(const float4*)(csr_w + (size_t)i * 4);
        uint v0 = *(const uint*)(h + (size_t)s0 * 128 + lane * 2);
        float a0 = bf2f_lo(v0), a1 = bf2f_hi(v0);
        acc[0][0] += w0.x * a0; acc[0][1] += w0.x * a1;
        acc[1][0] += w0.y * a0; acc[1][1] += w0.y * a1;
        acc[2][0] += w0.z * a0; acc[2][1] += w0.z * a1;
        acc[3][0] += w0.w * a0; acc[3][1] += w0.w * a1;
    }
#pragma unroll
    for (int k = 0; k < 4; ++k) {
        ushort2 p;
        p.x = f2bf(acc[k][0]);
        p.y = f2bf(acc[k][1]);
        *(ushort2*)(t + (size_t)n * 512 + k * 128 + lane * 2) = p;
    }
}

// ---------------- bf16 MFMA GEMM: C[M][128] = A[M][KD] @ Bt[128][KD]^T + bias ----------------
template <int KD, bool OUTBF>
__global__ __launch_bounds__(128) void mfma_gemm(const ushort* __restrict__ A,
                                                 const ushort* __restrict__ Bt,
                                                 const float* __restrict__ bias,
                                                 void* __restrict__ Cout, int M) {
    constexpr int PITCH = 40;  // 32 + 8 ushorts: 80 B rows, 16B-aligned, 2-way banks only
    __shared__ __align__(16) ushort As[64 * PITCH];
    __shared__ __align__(16) ushort Bs[128 * PITCH];
    int tid = threadIdx.x;
    int wave = tid >> 6, lane = tid & 63;
    int quad = lane >> 4, l16 = lane & 15;
    int m0 = blockIdx.x * 64;

    f32x4 acc[4][4];
#pragma unroll
    for (int r = 0; r < 4; ++r)
#pragma unroll
        for (int c = 0; c < 4; ++c) acc[r][c] = (f32x4){0.f, 0.f, 0.f, 0.f};

    for (int k0 = 0; k0 < KD; k0 += 32) {
#pragma unroll
        for (int it = 0; it < 2; ++it) {
            int chunk = it * 128 + tid;
            int row = chunk >> 2, off = chunk & 3;
            int gm = m0 + row;
            uint4 v = make_uint4(0u, 0u, 0u, 0u);
            if (gm < M) v = *(const uint4*)(A + (size_t)gm * KD + k0 + off * 8);
            *(uint4*)(As + row * PITCH + off * 8) = v;
        }
#pragma unroll
        for (int it = 0; it < 4; ++it) {
            int chunk = it * 128 + tid;
            int nr = chunk >> 2, off = chunk & 3;
            uint4 v = *(const uint4*)(Bt + (size_t)nr * KD + k0 + off * 8);
            *(uint4*)(Bs + nr * PITCH + off * 8) = v;
        }
        __syncthreads();

        bf16x8 afrag[4], bfrag[4];
#pragma unroll
        for (int r = 0; r < 4; ++r)
            afrag[r] = *(const bf16x8*)(As + (r * 16 + l16) * PITCH + quad * 8);
#pragma unroll
        for (int c = 0; c < 4; ++c)
            bfrag[c] = *(const bf16x8*)(Bs + (wave * 64 + c * 16 + l16) * PITCH + quad * 8);
#pragma unroll
        for (int r = 0; r < 4; ++r)
#pragma unroll
            for (int c = 0; c < 4; ++c)
                acc[r][c] = __builtin_amdgcn_mfma_f32_16x16x32_bf16(afrag[r], bfrag[c],
                                                                    acc[r][c], 0, 0, 0);
        __syncthreads();
    }

#pragma unroll
    for (int c = 0; c < 4; ++c) {
        int gn = wave * 64 + c * 16 + l16;
        float bv = bias[gn];
#pragma unroll
        for (int r = 0; r < 4; ++r) {
            int gmb = m0 + r * 16 + quad * 4;
#pragma unroll
            for (int i = 0; i < 4; ++i) {
                int gm = gmb + i;
                if (gm < M) {
                    float val = acc[r][c][i] + bv;
                    if (OUTBF)
                        ((ushort*)Cout)[(size_t)gm * 128 + gn] = f2bf(val);
                    else
                        ((float*)Cout)[(size_t)gm * 128 + gn] = val;
                }
            }
        }
    }
}

extern "C" void kernel_launch(void* const* d_in, const int* in_sizes, int n_in,
                              void* d_out, int out_size, void* d_ws, size_t ws_size,
                              hipStream_t stream) {
    const float* features = (const float*)d_in[0];
    const float* pseudo = (const float*)d_in[1];
    const int* src = (const int*)d_in[2];
    const int* dst = (const int*)d_in[3];
    const float* fc_w[3] = {(const float*)d_in[4], (const float*)d_in[10], (const float*)d_in[16]};
    const float* mu[3] = {(const float*)d_in[5], (const float*)d_in[11], (const float*)d_in[17]};
    const float* isg[3] = {(const float*)d_in[6], (const float*)d_in[12], (const float*)d_in[18]};
    const float* bias[3] = {(const float*)d_in[7], (const float*)d_in[13], (const float*)d_in[19]};
    const float* pw[3] = {(const float*)d_in[8], (const float*)d_in[14], (const float*)d_in[20]};
    const float* pb[3] = {(const float*)d_in[9], (const float*)d_in[15], (const float*)d_in[21]};

    char* ws = (char*)d_ws;
    auto alloc = [&](size_t bytes) -> void* {
        void* p = (void*)ws;
        ws += (bytes + 255) & ~(size_t)255;
        return p;
    };
    int* counts = (int*)alloc((size_t)NN * 4);
    int* offsets = (int*)alloc((size_t)(NN + 1) * 4);
    int* cursor = (int*)alloc((size_t)NN * 4);
    int* csr_eidx = (int*)alloc((size_t)NE * 4);
    int* csr_src = (int*)alloc((size_t)NE * 4);
    float* csr_w = (float*)alloc((size_t)3 * NE * 4 * 4);
    ushort* w2t_0 = (ushort*)alloc((size_t)128 * 256 * 2);
    ushort* w2t_1 = (ushort*)alloc((size_t)128 * 512 * 2);
    ushort* w2t_2 = (ushort*)alloc((size_t)128 * 512 * 2);
    ushort* tbuf = (ushort*)alloc((size_t)NN * 512 * 2);
    ushort* h1 = (ushort*)alloc((size_t)NN * 128 * 2);
    ushort* h2 = (ushort*)alloc((size_t)NN * 128 * 2);

    hipMemsetAsync(counts, 0, (size_t)NN * 4, stream);
    count_kernel<<<(NE + 255) / 256, 256, 0, stream>>>(dst, counts);
    scan_kernel<<<1, 1024, 0, stream>>>(counts, offsets, cursor);
    fill1_kernel<<<(NE + 255) / 256, 256, 0, stream>>>(dst, cursor, csr_eidx);

    EdgeParams P;
    P.pw0 = pw[0]; P.pb0 = pb[0]; P.mu0 = mu[0]; P.is0 = isg[0];
    P.pw1 = pw[1]; P.pb1 = pb[1]; P.mu1 = mu[1]; P.is1 = isg[1];
    P.pw2 = pw[2]; P.pb2 = pb[2]; P.mu2 = mu[2]; P.is2 = isg[2];
    fill2_kernel<<<(NE + 255) / 256, 256, 0, stream>>>(csr_eidx, src, pseudo, P, csr_src, csr_w);

    const int PT = 128 * 256 + 2 * 128 * 512;
    prep_all<<<(PT + 255) / 256, 256, 0, stream>>>(fc_w[0], fc_w[1], fc_w[2], w2t_0, w2t_1, w2t_2);

    const int GB = (NN + 63) / 64;  // 313

    // layer 0: din=64, KD=256
    agg_f32_64<<<NN, 64, 0, stream>>>(features, offsets, csr_src, csr_w + (size_t)0 * NE * 4, tbuf);
    mfma_gemm<256, true><<<GB, 128, 0, stream>>>(tbuf, w2t_0, bias[0], h1, NN);
    // layer 1: din=128, KD=512
    agg_bf_128<<<NN, 64, 0, stream>>>(h1, offsets, csr_src, csr_w + (size_t)1 * NE * 4, tbuf);
    mfma_gemm<512, true><<<GB, 128, 0, stream>>>(tbuf, w2t_1, bias[1], h2, NN);
    // layer 2: din=128, KD=512
    agg_bf_128<<<NN, 64, 0, stream>>>(h2, offsets, csr_src, csr_w + (size_t)2 * NE * 4, tbuf);
    mfma_gemm<512, false><<<GB, 128, 0, stream>>>(tbuf, w2t_2, bias[2], (float*)d_out, NN);
}